// Round 5
// baseline (6459.768 us; speedup 1.0000x reference)
//
#include <hip/hip_runtime.h>
#include <math.h>

#define N_NODES 50000
#define N_EDGES 800000

__device__ __forceinline__ float silu_f(float x) {
    return x * __fdividef(1.f, 1.f + __expf(-x));
}

// ---------------- K1: per-node pre (s1,v1 -> ws; sc_s,sc_v -> out) ----------
__global__ void __launch_bounds__(256) k_node_pre(
    const float* __restrict__ node_feats,
    const int*   __restrict__ specie,
    const float* __restrict__ Wus,   // 32x32
    const float* __restrict__ Wuv,   // 32x32
    const float* __restrict__ Wss,   // 5x32x32
    const float* __restrict__ Wsv,   // 5x32x32
    float* __restrict__ s1v1,        // N x 128  [s1(32), v1 m*3+c (96)]
    float* __restrict__ out)         // N x 128  gets sc
{
    int n = blockIdx.x * 256 + threadIdx.x;
    if (n >= N_NODES) return;
    int part = blockIdx.y;           // 0 = scalar part, 1..3 = vector c
    const float* nf = node_feats + (size_t)n * 128;
    float* srow = s1v1 + (size_t)n * 128;
    float* orow = out  + (size_t)n * 128;
    int sp = specie[n];
    const float RS32 = 0.17677669529663687f; // 1/sqrt(32)

    if (part == 0) {
        float s[32];
        #pragma unroll
        for (int q = 0; q < 8; ++q) {
            float4 t = *reinterpret_cast<const float4*>(nf + 4*q);
            s[4*q+0]=t.x; s[4*q+1]=t.y; s[4*q+2]=t.z; s[4*q+3]=t.w;
        }
        float acc[32];
        #pragma unroll
        for (int k = 0; k < 32; ++k) acc[k] = 0.f;
        #pragma unroll
        for (int m = 0; m < 32; ++m) {
            float sm = s[m];
            #pragma unroll
            for (int k = 0; k < 32; ++k) acc[k] += sm * Wus[m*32 + k];
        }
        #pragma unroll
        for (int k = 0; k < 32; ++k) srow[k] = acc[k] * RS32;

        const float* Wp = Wss + sp * 1024;
        #pragma unroll
        for (int k = 0; k < 32; ++k) acc[k] = 0.f;
        #pragma unroll
        for (int i = 0; i < 32; ++i) {
            float si = s[i];
            #pragma unroll
            for (int j = 0; j < 32; ++j) acc[j] += si * __ldg(Wp + i*32 + j);
        }
        #pragma unroll
        for (int j = 0; j < 32; ++j) orow[j] = acc[j] * RS32;
    } else {
        int c = part - 1;
        float v[32];
        #pragma unroll
        for (int m = 0; m < 32; ++m) v[m] = nf[32 + m*3 + c];
        float acc[32];
        #pragma unroll
        for (int k = 0; k < 32; ++k) acc[k] = 0.f;
        #pragma unroll
        for (int m = 0; m < 32; ++m) {
            float vm = v[m];
            #pragma unroll
            for (int k = 0; k < 32; ++k) acc[k] += vm * Wuv[m*32 + k];
        }
        #pragma unroll
        for (int k = 0; k < 32; ++k) srow[32 + k*3 + c] = acc[k] * RS32;

        const float* Wp = Wsv + sp * 1024;
        #pragma unroll
        for (int k = 0; k < 32; ++k) acc[k] = 0.f;
        #pragma unroll
        for (int m = 0; m < 32; ++m) {
            float vm = v[m];
            #pragma unroll
            for (int k = 0; k < 32; ++k) acc[k] += vm * __ldg(Wp + m*32 + k);
        }
        #pragma unroll
        for (int k = 0; k < 32; ++k) orow[32 + k*3 + c] = acc[k] * RS32;
    }
}

// ---------------- sort stage: histogram -> scan -> scatter ------------------
__global__ void __launch_bounds__(256) k_hist(
    const int* __restrict__ receivers, int* __restrict__ cnt)
{
    int e = blockIdx.x * 256 + threadIdx.x;   // grid exact: 3125*256 = 800000
    atomicAdd(&cnt[receivers[e]], 1);
}

__global__ void __launch_bounds__(1024) k_scan(
    const int* __restrict__ cnt, int* __restrict__ off, int* __restrict__ cursor)
{
    __shared__ int lds[1024];
    __shared__ int base_s;
    int t = threadIdx.x;
    if (t == 0) base_s = 0;
    __syncthreads();
    for (int start = 0; start < N_NODES; start += 1024) {
        int i = start + t;
        int c = (i < N_NODES) ? cnt[i] : 0;
        lds[t] = c;
        __syncthreads();
        for (int d = 1; d < 1024; d <<= 1) {
            int v = (t >= d) ? lds[t - d] : 0;
            __syncthreads();
            lds[t] += v;
            __syncthreads();
        }
        int excl = base_s + lds[t] - c;
        if (i < N_NODES) { off[i] = excl; cursor[i] = 0; }
        __syncthreads();
        if (t == 0) base_s += lds[1023];
        __syncthreads();
    }
    if (t == 0) off[N_NODES] = base_s;
}

__global__ void __launch_bounds__(256) k_scatter(
    const float* __restrict__ vectors, const int* __restrict__ senders,
    const int* __restrict__ receivers, const int* __restrict__ off,
    int* __restrict__ cursor, float4* __restrict__ sortedVS)
{
    int e = blockIdx.x * 256 + threadIdx.x;   // grid exact
    int r = receivers[e];
    int pos = off[r] + atomicAdd(&cursor[r], 1);
    float4 vs;
    vs.x = vectors[3*e+0]; vs.y = vectors[3*e+1]; vs.z = vectors[3*e+2];
    vs.w = __int_as_float(senders[e]);
    sortedVS[pos] = vs;
}

// ---------------- K2: per-slot edge kernel, TRANSPOSED message planes ------
// msgs_T[comp j][row p] with plane stride ld; lanes have consecutive p ->
// every store is a coalesced 256B wave-store.
__global__ void __launch_bounds__(256) k_edge(
    const float4* __restrict__ sortedVS,
    const float* __restrict__ W1,    // 8x64
    const float* __restrict__ W2,    // 64x64
    const float* __restrict__ W3,    // 64x64
    const float* __restrict__ W4,    // 64x128
    const float* __restrict__ s1v1,  // N x 128
    float* __restrict__ msgsT,       // 256 x ld
    int r0, int r1, int ld)
{
    int slot = r0 + blockIdx.x * 256 + threadIdx.x;
    if (slot >= r1) return;
    float4 vs = sortedVS[slot];

    float vx = vs.x, vy = vs.y, vz = vs.z;
    int snd = __float_as_int(vs.w);

    float x2 = vx*vx + vy*vy + vz*vz;
    float len = sqrtf(x2 == 0.f ? 1.f : x2);
    float invl = 1.f / len;
    float l2 = len*len, l3 = l2*len, l6 = l3*l3;
    float env = (len < 1.f) ? (1.f - 28.f*l6 + 48.f*l6*len - 21.f*l6*l2) : 0.f;

    const float SQRT2 = 1.4142135623730951f;
    const float PI    = 3.14159265358979f;
    float radial[8];
    #pragma unroll
    for (int nb = 0; nb < 8; ++nb)
        radial[nb] = SQRT2 * __sinf(PI * (float)(nb+1) * len) * invl * env;

    const float SQ3 = 1.7320508075688772f;
    float shx = SQ3 * vx * invl;
    float shy = SQ3 * vy * invl;
    float shz = SQ3 * vz * invl;

    const float RS8  = 0.35355339059327373f;  // 1/sqrt(8)
    const float RS64 = 0.125f;                // 1/sqrt(64)
    const float RS3  = 0.5773502691896258f;   // 1/sqrt(3)

    float A[64], B[64];

    // layer 1 -> A (h1)
    #pragma unroll
    for (int j = 0; j < 64; ++j) A[j] = 0.f;
    #pragma unroll
    for (int i2 = 0; i2 < 8; ++i2) {
        float hi = radial[i2];
        #pragma unroll
        for (int j = 0; j < 64; ++j) A[j] += hi * W1[i2*64 + j];
    }
    #pragma unroll
    for (int j = 0; j < 64; ++j) A[j] = silu_f(A[j] * RS8);

    // layer 2 -> B (h2)
    #pragma unroll
    for (int j = 0; j < 64; ++j) B[j] = 0.f;
    #pragma unroll
    for (int i2 = 0; i2 < 64; ++i2) {
        float hi = A[i2];
        #pragma unroll
        for (int j = 0; j < 64; ++j) B[j] += hi * W2[i2*64 + j];
    }
    #pragma unroll
    for (int j = 0; j < 64; ++j) B[j] = silu_f(B[j] * RS64);

    // layer 3 -> A (h3)
    #pragma unroll
    for (int j = 0; j < 64; ++j) A[j] = 0.f;
    #pragma unroll
    for (int i2 = 0; i2 < 64; ++i2) {
        float hi = B[i2];
        #pragma unroll
        for (int j = 0; j < 64; ++j) A[j] += hi * W3[i2*64 + j];
    }
    #pragma unroll
    for (int j = 0; j < 64; ++j) A[j] = silu_f(A[j] * RS64);

    // mix_v (cols 64..128) -> B
    #pragma unroll
    for (int j = 0; j < 64; ++j) B[j] = 0.f;
    #pragma unroll
    for (int i2 = 0; i2 < 64; ++i2) {
        float hi = A[i2];
        #pragma unroll
        for (int j = 0; j < 64; ++j) B[j] += hi * W4[i2*128 + 64 + j];
    }
    #pragma unroll
    for (int j = 0; j < 64; ++j) B[j] *= RS64;

    const float* srow = s1v1 + (size_t)snd * 128;
    float* mp = msgsT + (slot - r0);     // column for this row

    // ms -> C
    float C[32];
    #pragma unroll
    for (int q = 0; q < 8; ++q) {
        float4 t = *reinterpret_cast<const float4*>(srow + 4*q);
        C[4*q+0]=t.x; C[4*q+1]=t.y; C[4*q+2]=t.z; C[4*q+3]=t.w;
    }

    // tp_v rows (v rows 32..63): comps at 160 + 3m + c
    #pragma unroll
    for (int m = 0; m < 32; ++m) {
        float f = C[m] * B[32+m];
        mp[(size_t)(160 + 3*m + 0) * ld] = f*shx;
        mp[(size_t)(160 + 3*m + 1) * ld] = f*shy;
        mp[(size_t)(160 + 3*m + 2) * ld] = f*shz;
    }

    // mv rows (v rows 0..31): comps at 64 + 3m + c; also tp_s -> D
    float D[32];
    #pragma unroll
    for (int b = 0; b < 4; ++b) {
        float bat[24];
        #pragma unroll
        for (int q = 0; q < 6; ++q) {
            float4 t = *reinterpret_cast<const float4*>(srow + 32 + b*24 + 4*q);
            bat[4*q+0]=t.x; bat[4*q+1]=t.y; bat[4*q+2]=t.z; bat[4*q+3]=t.w;
        }
        #pragma unroll
        for (int mm = 0; mm < 8; ++mm) {
            int m = b*8 + mm;
            float mvx = bat[3*mm+0], mvy = bat[3*mm+1], mvz = bat[3*mm+2];
            D[m] = (mvx*shx + mvy*shy + mvz*shz) * RS3;
            float f = B[m];
            mp[(size_t)(64 + 3*m + 0) * ld] = mvx*f;
            mp[(size_t)(64 + 3*m + 1) * ld] = mvy*f;
            mp[(size_t)(64 + 3*m + 2) * ld] = mvz*f;
        }
    }

    // mix_s (cols 0..64) -> B
    #pragma unroll
    for (int j = 0; j < 64; ++j) B[j] = 0.f;
    #pragma unroll
    for (int i2 = 0; i2 < 64; ++i2) {
        float hi = A[i2];
        #pragma unroll
        for (int j = 0; j < 64; ++j) B[j] += hi * W4[i2*128 + j];
    }
    #pragma unroll
    for (int j = 0; j < 64; ++j) B[j] *= RS64;

    // scalar message: [ms*mix_s (0..31), tp_s*mix_s (32..63)]
    #pragma unroll
    for (int j = 0; j < 32; ++j) mp[(size_t)j * ld]        = C[j] * B[j];
    #pragma unroll
    for (int j = 0; j < 32; ++j) mp[(size_t)(32 + j) * ld] = D[j] * B[32+j];
}

// ---------------- K2b: per-(node,comp) accumulate from transposed planes ----
// grid: (ceil(N/64), 4 comp-quarters); block 256 = 64 nodes x 4 comp-groups.
__global__ void __launch_bounds__(256) k_agg(
    const float* __restrict__ msgsT,
    const int*   __restrict__ off,
    float* __restrict__ agg,         // N x 256
    int r0, int r1, int ld, int first)
{
    int t = threadIdx.x;
    int n = blockIdx.x * 64 + (t & 63);
    if (n >= N_NODES) return;
    int jg = t >> 6;                       // 0..3
    int jbase = blockIdx.y * 64 + jg * 16; // 16 comps per thread
    int p0 = off[n], p1 = off[n+1];
    int lo = p0 > r0 ? p0 : r0;
    int hi = p1 < r1 ? p1 : r1;
    if (!first && lo >= hi) return;
    float* ap = agg + (size_t)n * 256 + jbase;
    #pragma unroll
    for (int jj = 0; jj < 16; ++jj) {
        const float* plane = msgsT + (size_t)(jbase + jj) * ld - r0;
        float s = 0.f;
        for (int p = lo; p < hi; ++p) s += plane[p];
        if (first) ap[jj] = s;
        else       ap[jj] += s;
    }
}

// ---------------- K3: per-node post (down-proj, gate, += into out) ----------
__global__ void __launch_bounds__(256) k_node_post(
    const float* __restrict__ agg,   // N x 256
    const float* __restrict__ Wds,   // 64x64
    const float* __restrict__ Wdv,   // 64x32
    float* __restrict__ out)         // N x 128 (holds sc from K1)
{
    int n = blockIdx.x;
    int t = threadIdx.x;
    __shared__ float a_s[256];
    __shared__ float gl[32];

    a_s[t] = agg[(size_t)n * 256 + t];
    __syncthreads();

    const float SC = 0.03125f;       // (1/sqrt(16)) * (1/sqrt(64))
    float* orow = out + (size_t)n * 128;

    float dv = 0.f;
    if (t < 64) {
        float acc = 0.f;
        #pragma unroll
        for (int m = 0; m < 64; ++m) acc += a_s[m] * Wds[m*64 + t];
        float sv = silu_f(acc * SC);
        if (t < 32) orow[t] += sv;       // feat + sc_s
        else        gl[t - 32] = sv;     // g
    } else if (t < 160) {
        int kc = t - 64;                 // = k*3 + c
        int k = kc / 3, c = kc - 3*k;
        float acc = 0.f;
        #pragma unroll
        for (int m = 0; m < 64; ++m) acc += a_s[64 + m*3 + c] * Wdv[m*32 + k];
        dv = acc * SC;
    }
    __syncthreads();
    if (t >= 64 && t < 160) {
        int kc = t - 64;
        int k = kc / 3;
        orow[32 + kc] += dv * gl[k];     // gv + sc_v
    }
}

extern "C" void kernel_launch(void* const* d_in, const int* in_sizes, int n_in,
                              void* d_out, int out_size, void* d_ws, size_t ws_size,
                              hipStream_t stream) {
    const float* vectors    = (const float*)d_in[0];
    const float* node_feats = (const float*)d_in[1];
    const float* W_skip_s   = (const float*)d_in[2];
    const float* W_skip_v   = (const float*)d_in[3];
    const float* W_up_s     = (const float*)d_in[4];
    const float* W_up_v     = (const float*)d_in[5];
    const float* W_mlp1     = (const float*)d_in[6];
    const float* W_mlp2     = (const float*)d_in[7];
    const float* W_mlp3     = (const float*)d_in[8];
    const float* W_mlp4     = (const float*)d_in[9];
    const float* W_down_s   = (const float*)d_in[10];
    const float* W_down_v   = (const float*)d_in[11];
    const int*   node_specie= (const int*)d_in[12];
    const int*   senders    = (const int*)d_in[13];
    const int*   receivers  = (const int*)d_in[14];
    float* out = (float*)d_out;

    // workspace layout
    float*  s1v1     = (float*)d_ws;                                  // N*128
    float*  agg      = s1v1 + (size_t)N_NODES * 128;                  // N*256
    float4* sortedVS = (float4*)(agg + (size_t)N_NODES * 256);        // E
    int*    cnt      = (int*)(sortedVS + N_EDGES);                    // N
    int*    cursor   = cnt + N_NODES;                                 // N
    int*    off      = cursor + N_NODES;                              // N+1
    float*  msgs     = (float*)(off + N_NODES + 2);                   // chunked

    size_t base_bytes = (size_t)((char*)msgs - (char*)d_ws);
    size_t avail = (ws_size > base_bytes + 4096) ? (ws_size - base_bytes - 4096) : 0;
    long cap = (long)(avail / 1024);            // 256 floats per row
    if (cap > N_EDGES) cap = N_EDGES;
    if (cap < 4096)    cap = 4096;              // assume ws >= ~100 MB
    int chunks = (int)((N_EDGES + cap - 1) / cap);
    int rows   = (N_EDGES + chunks - 1) / chunks;   // = plane stride ld

    hipMemsetAsync(cnt, 0, (size_t)N_NODES * sizeof(int), stream);

    dim3 gn((N_NODES + 255) / 256, 4);
    k_node_pre<<<gn, 256, 0, stream>>>(node_feats, node_specie, W_up_s, W_up_v,
                                       W_skip_s, W_skip_v, s1v1, out);
    k_hist<<<N_EDGES / 256, 256, 0, stream>>>(receivers, cnt);
    k_scan<<<1, 1024, 0, stream>>>(cnt, off, cursor);
    k_scatter<<<N_EDGES / 256, 256, 0, stream>>>(vectors, senders, receivers,
                                                 off, cursor, sortedVS);
    dim3 ga((N_NODES + 63) / 64, 4);
    for (int c = 0; c < chunks; ++c) {
        int r0 = c * rows;
        int r1 = r0 + rows; if (r1 > N_EDGES) r1 = N_EDGES;
        int nb = (r1 - r0 + 255) / 256;
        k_edge<<<nb, 256, 0, stream>>>(sortedVS, W_mlp1, W_mlp2, W_mlp3, W_mlp4,
                                       s1v1, msgs, r0, r1, rows);
        k_agg<<<ga, 256, 0, stream>>>(msgs, off, agg, r0, r1, rows, (c == 0) ? 1 : 0);
    }
    k_node_post<<<N_NODES, 256, 0, stream>>>(agg, W_down_s, W_down_v, out);
}

// Round 6
// 5535.466 us; speedup vs baseline: 1.1670x; 1.1670x over previous
//
#include <hip/hip_runtime.h>
#include <math.h>

#define N_NODES 50000
#define N_EDGES 800000
#define W_LDS_BYTES 67584   // (512+4096+4096+8192) floats

__device__ __forceinline__ float silu_f(float x) {
    return x * __fdividef(1.f, 1.f + __expf(-x));
}

// dense fp32 layer: weights in LDS (uniform ds_read_b128 at const offsets)
template<int NIN, int NOUT, int LDW>
__device__ __forceinline__ void layer_fp32(const float* Wl,
                                           const float (&in)[NIN], float (&out)[NOUT])
{
    #pragma unroll
    for (int j = 0; j < NOUT; ++j) out[j] = 0.f;
    #pragma unroll
    for (int i = 0; i < NIN; ++i) {
        float hi = in[i];
        #pragma unroll
        for (int jq = 0; jq < NOUT/4; ++jq) {
            float4 w = *reinterpret_cast<const float4*>(Wl + i*LDW + 4*jq);
            out[4*jq+0] += hi*w.x; out[4*jq+1] += hi*w.y;
            out[4*jq+2] += hi*w.z; out[4*jq+3] += hi*w.w;
        }
    }
}

// ---------------- K1: per-node pre (s1,v1 -> ws; sc_s,sc_v -> out) ----------
__global__ void __launch_bounds__(256) k_node_pre(
    const float* __restrict__ node_feats,
    const int*   __restrict__ specie,
    const float* __restrict__ Wus,   // 32x32
    const float* __restrict__ Wuv,   // 32x32
    const float* __restrict__ Wss,   // 5x32x32
    const float* __restrict__ Wsv,   // 5x32x32
    float* __restrict__ s1v1,        // N x 128  [s1(32), v1 m*3+c (96)]
    float* __restrict__ out)         // N x 128  gets sc
{
    int n = blockIdx.x * 256 + threadIdx.x;
    if (n >= N_NODES) return;
    int part = blockIdx.y;           // 0 = scalar part, 1..3 = vector c
    const float* nf = node_feats + (size_t)n * 128;
    float* srow = s1v1 + (size_t)n * 128;
    float* orow = out  + (size_t)n * 128;
    int sp = specie[n];
    const float RS32 = 0.17677669529663687f; // 1/sqrt(32)

    if (part == 0) {
        float s[32];
        #pragma unroll
        for (int q = 0; q < 8; ++q) {
            float4 t = *reinterpret_cast<const float4*>(nf + 4*q);
            s[4*q+0]=t.x; s[4*q+1]=t.y; s[4*q+2]=t.z; s[4*q+3]=t.w;
        }
        float acc[32];
        #pragma unroll
        for (int k = 0; k < 32; ++k) acc[k] = 0.f;
        #pragma unroll
        for (int m = 0; m < 32; ++m) {
            float sm = s[m];
            #pragma unroll
            for (int k = 0; k < 32; ++k) acc[k] += sm * Wus[m*32 + k];
        }
        #pragma unroll
        for (int k = 0; k < 32; ++k) srow[k] = acc[k] * RS32;

        const float* Wp = Wss + sp * 1024;
        #pragma unroll
        for (int k = 0; k < 32; ++k) acc[k] = 0.f;
        #pragma unroll
        for (int i = 0; i < 32; ++i) {
            float si = s[i];
            #pragma unroll
            for (int j = 0; j < 32; ++j) acc[j] += si * __ldg(Wp + i*32 + j);
        }
        #pragma unroll
        for (int j = 0; j < 32; ++j) orow[j] = acc[j] * RS32;
    } else {
        int c = part - 1;
        float v[32];
        #pragma unroll
        for (int m = 0; m < 32; ++m) v[m] = nf[32 + m*3 + c];
        float acc[32];
        #pragma unroll
        for (int k = 0; k < 32; ++k) acc[k] = 0.f;
        #pragma unroll
        for (int m = 0; m < 32; ++m) {
            float vm = v[m];
            #pragma unroll
            for (int k = 0; k < 32; ++k) acc[k] += vm * Wuv[m*32 + k];
        }
        #pragma unroll
        for (int k = 0; k < 32; ++k) srow[32 + k*3 + c] = acc[k] * RS32;

        const float* Wp = Wsv + sp * 1024;
        #pragma unroll
        for (int k = 0; k < 32; ++k) acc[k] = 0.f;
        #pragma unroll
        for (int m = 0; m < 32; ++m) {
            float vm = v[m];
            #pragma unroll
            for (int k = 0; k < 32; ++k) acc[k] += vm * __ldg(Wp + m*32 + k);
        }
        #pragma unroll
        for (int k = 0; k < 32; ++k) orow[32 + k*3 + c] = acc[k] * RS32;
    }
}

// ---------------- sort stage: histogram -> scan -> scatter ------------------
__global__ void __launch_bounds__(256) k_hist(
    const int* __restrict__ receivers, int* __restrict__ cnt)
{
    int e = blockIdx.x * 256 + threadIdx.x;   // grid exact: 3125*256 = 800000
    atomicAdd(&cnt[receivers[e]], 1);
}

__global__ void __launch_bounds__(1024) k_scan(
    const int* __restrict__ cnt, int* __restrict__ off, int* __restrict__ cursor)
{
    __shared__ int lds[1024];
    __shared__ int base_s;
    int t = threadIdx.x;
    if (t == 0) base_s = 0;
    __syncthreads();
    for (int start = 0; start < N_NODES; start += 1024) {
        int i = start + t;
        int c = (i < N_NODES) ? cnt[i] : 0;
        lds[t] = c;
        __syncthreads();
        for (int d = 1; d < 1024; d <<= 1) {
            int v = (t >= d) ? lds[t - d] : 0;
            __syncthreads();
            lds[t] += v;
            __syncthreads();
        }
        int excl = base_s + lds[t] - c;
        if (i < N_NODES) { off[i] = excl; cursor[i] = 0; }
        __syncthreads();
        if (t == 0) base_s += lds[1023];
        __syncthreads();
    }
    if (t == 0) off[N_NODES] = base_s;
}

__global__ void __launch_bounds__(256) k_scatter(
    const float* __restrict__ vectors, const int* __restrict__ senders,
    const int* __restrict__ receivers, const int* __restrict__ off,
    int* __restrict__ cursor, float4* __restrict__ sortedVS)
{
    int e = blockIdx.x * 256 + threadIdx.x;   // grid exact
    int r = receivers[e];
    int pos = off[r] + atomicAdd(&cursor[r], 1);
    float4 vs;
    vs.x = vectors[3*e+0]; vs.y = vectors[3*e+1]; vs.z = vectors[3*e+2];
    vs.w = __int_as_float(senders[e]);
    sortedVS[pos] = vs;
}

// ---------------- K2: per-slot edge kernel -----------------------------------
// msgs blocked-transposed: tile = 64 rows; layout [tile][comp(256)][row(64)]
// -> each wave-store is one coalesced 256B within a 64KB tile.
__global__ void __launch_bounds__(256) k_edge(
    const float4* __restrict__ sortedVS,
    const float* __restrict__ W1,    // 8x64
    const float* __restrict__ W2,    // 64x64
    const float* __restrict__ W3,    // 64x64
    const float* __restrict__ W4,    // 64x128
    const float* __restrict__ s1v1,  // N x 128
    float* __restrict__ msgs,
    int r0, int r1)
{
    extern __shared__ float wl[];
    float* Wl1 = wl;            // 512
    float* Wl2 = wl + 512;      // 4096
    float* Wl3 = wl + 4608;     // 4096
    float* Wl4 = wl + 8704;     // 8192
    int t = threadIdx.x;
    {
        const float4* g1 = reinterpret_cast<const float4*>(W1);
        float4* l1 = reinterpret_cast<float4*>(Wl1);
        for (int i = t; i < 128;  i += 256) l1[i] = g1[i];
        const float4* g2 = reinterpret_cast<const float4*>(W2);
        float4* l2 = reinterpret_cast<float4*>(Wl2);
        for (int i = t; i < 1024; i += 256) l2[i] = g2[i];
        const float4* g3 = reinterpret_cast<const float4*>(W3);
        float4* l3 = reinterpret_cast<float4*>(Wl3);
        for (int i = t; i < 1024; i += 256) l3[i] = g3[i];
        const float4* g4 = reinterpret_cast<const float4*>(W4);
        float4* l4 = reinterpret_cast<float4*>(Wl4);
        for (int i = t; i < 2048; i += 256) l4[i] = g4[i];
    }
    __syncthreads();

    int slot = r0 + blockIdx.x * 256 + t;
    if (slot >= r1) return;      // after sync: safe

    float4 vs = sortedVS[slot];
    float vx = vs.x, vy = vs.y, vz = vs.z;
    int snd = __float_as_int(vs.w);

    float x2 = vx*vx + vy*vy + vz*vz;
    float len = sqrtf(x2 == 0.f ? 1.f : x2);
    float invl = 1.f / len;
    float l2v = len*len, l3v = l2v*len, l6 = l3v*l3v;
    float env = (len < 1.f) ? (1.f - 28.f*l6 + 48.f*l6*len - 21.f*l6*l2v) : 0.f;

    const float SQRT2 = 1.4142135623730951f;
    const float PI    = 3.14159265358979f;
    float radial[8];
    #pragma unroll
    for (int nb = 0; nb < 8; ++nb)
        radial[nb] = SQRT2 * __sinf(PI * (float)(nb+1) * len) * invl * env;

    const float SQ3 = 1.7320508075688772f;
    float shx = SQ3 * vx * invl;
    float shy = SQ3 * vy * invl;
    float shz = SQ3 * vz * invl;

    const float RS8  = 0.35355339059327373f;  // 1/sqrt(8)
    const float RS64 = 0.125f;                // 1/sqrt(64)
    const float RS3  = 0.5773502691896258f;   // 1/sqrt(3)

    float A[64], B[64];

    // layer 1 -> A (h1)
    layer_fp32<8,64,64>(Wl1, radial, A);
    #pragma unroll
    for (int j = 0; j < 64; ++j) A[j] = silu_f(A[j] * RS8);

    // layer 2 -> B (h2)
    layer_fp32<64,64,64>(Wl2, A, B);
    #pragma unroll
    for (int j = 0; j < 64; ++j) B[j] = silu_f(B[j] * RS64);

    // layer 3 -> A (h3)
    layer_fp32<64,64,64>(Wl3, B, A);
    #pragma unroll
    for (int j = 0; j < 64; ++j) A[j] = silu_f(A[j] * RS64);

    // mix_v (cols 64..128) -> B
    layer_fp32<64,64,128>(Wl4 + 64, A, B);
    #pragma unroll
    for (int j = 0; j < 64; ++j) B[j] *= RS64;

    const float* srow = s1v1 + (size_t)snd * 128;
    int rrel = slot - r0;
    float* mp = msgs + (((size_t)(rrel >> 6)) << 14) + (rrel & 63);  // tile*16384 + lane

    // ms -> C
    float C[32];
    #pragma unroll
    for (int q = 0; q < 8; ++q) {
        float4 tt = *reinterpret_cast<const float4*>(srow + 4*q);
        C[4*q+0]=tt.x; C[4*q+1]=tt.y; C[4*q+2]=tt.z; C[4*q+3]=tt.w;
    }

    // tp_v rows (v rows 32..63): comps 160 + 3m + c
    #pragma unroll
    for (int m = 0; m < 32; ++m) {
        float f = C[m] * B[32+m];
        mp[(160 + 3*m + 0) * 64] = f*shx;
        mp[(160 + 3*m + 1) * 64] = f*shy;
        mp[(160 + 3*m + 2) * 64] = f*shz;
    }

    // mv rows (v rows 0..31): comps 64 + 3m + c; also tp_s -> D
    float D[32];
    #pragma unroll
    for (int b = 0; b < 4; ++b) {
        float bat[24];
        #pragma unroll
        for (int q = 0; q < 6; ++q) {
            float4 tt = *reinterpret_cast<const float4*>(srow + 32 + b*24 + 4*q);
            bat[4*q+0]=tt.x; bat[4*q+1]=tt.y; bat[4*q+2]=tt.z; bat[4*q+3]=tt.w;
        }
        #pragma unroll
        for (int mm = 0; mm < 8; ++mm) {
            int m = b*8 + mm;
            float mvx = bat[3*mm+0], mvy = bat[3*mm+1], mvz = bat[3*mm+2];
            D[m] = (mvx*shx + mvy*shy + mvz*shz) * RS3;
            float f = B[m];
            mp[(64 + 3*m + 0) * 64] = mvx*f;
            mp[(64 + 3*m + 1) * 64] = mvy*f;
            mp[(64 + 3*m + 2) * 64] = mvz*f;
        }
    }

    // mix_s (cols 0..64) -> B
    layer_fp32<64,64,128>(Wl4, A, B);
    #pragma unroll
    for (int j = 0; j < 64; ++j) B[j] *= RS64;

    // scalar message: [ms*mix_s (0..31), tp_s*mix_s (32..63)]
    #pragma unroll
    for (int j = 0; j < 32; ++j) mp[j * 64]        = C[j] * B[j];
    #pragma unroll
    for (int j = 0; j < 32; ++j) mp[(32 + j) * 64] = D[j] * B[32+j];
}

// ---------------- K2b: per-(node,comp) accumulate, blocked layout -----------
__global__ void __launch_bounds__(256) k_agg(
    const float* __restrict__ msgs,
    const int*   __restrict__ off,
    float* __restrict__ agg,         // N x 256
    int r0, int r1, int first)
{
    int t = threadIdx.x;
    int n = blockIdx.x * 64 + (t & 63);
    if (n >= N_NODES) return;
    int jg = t >> 6;                       // 0..3
    int jbase = blockIdx.y * 64 + jg * 16; // 16 comps per thread
    int p0 = off[n], p1 = off[n+1];
    int lo = p0 > r0 ? p0 : r0;
    int hi = p1 < r1 ? p1 : r1;
    if (!first && lo >= hi) return;
    float* ap = agg + (size_t)n * 256 + jbase;
    #pragma unroll
    for (int jj = 0; jj < 16; ++jj) {
        int comp = jbase + jj;
        float s = 0.f;
        for (int p = lo; p < hi; ++p) {
            int prel = p - r0;
            s += msgs[(((size_t)(prel >> 6)) << 14) + (comp << 6) + (prel & 63)];
        }
        if (first) ap[jj] = s;
        else       ap[jj] += s;
    }
}

// ---------------- K3: per-node post (down-proj, gate, += into out) ----------
__global__ void __launch_bounds__(256) k_node_post(
    const float* __restrict__ agg,   // N x 256
    const float* __restrict__ Wds,   // 64x64
    const float* __restrict__ Wdv,   // 64x32
    float* __restrict__ out)         // N x 128 (holds sc from K1)
{
    int n = blockIdx.x;
    int t = threadIdx.x;
    __shared__ float a_s[256];
    __shared__ float gl[32];

    a_s[t] = agg[(size_t)n * 256 + t];
    __syncthreads();

    const float SC = 0.03125f;       // (1/sqrt(16)) * (1/sqrt(64))
    float* orow = out + (size_t)n * 128;

    float dv = 0.f;
    if (t < 64) {
        float acc = 0.f;
        #pragma unroll
        for (int m = 0; m < 64; ++m) acc += a_s[m] * Wds[m*64 + t];
        float sv = silu_f(acc * SC);
        if (t < 32) orow[t] += sv;       // feat + sc_s
        else        gl[t - 32] = sv;     // g
    } else if (t < 160) {
        int kc = t - 64;                 // = k*3 + c
        int k = kc / 3, c = kc - 3*k;
        float acc = 0.f;
        #pragma unroll
        for (int m = 0; m < 64; ++m) acc += a_s[64 + m*3 + c] * Wdv[m*32 + k];
        dv = acc * SC;
    }
    __syncthreads();
    if (t >= 64 && t < 160) {
        int kc = t - 64;
        int k = kc / 3;
        orow[32 + kc] += dv * gl[k];     // gv + sc_v
    }
}

extern "C" void kernel_launch(void* const* d_in, const int* in_sizes, int n_in,
                              void* d_out, int out_size, void* d_ws, size_t ws_size,
                              hipStream_t stream) {
    const float* vectors    = (const float*)d_in[0];
    const float* node_feats = (const float*)d_in[1];
    const float* W_skip_s   = (const float*)d_in[2];
    const float* W_skip_v   = (const float*)d_in[3];
    const float* W_up_s     = (const float*)d_in[4];
    const float* W_up_v     = (const float*)d_in[5];
    const float* W_mlp1     = (const float*)d_in[6];
    const float* W_mlp2     = (const float*)d_in[7];
    const float* W_mlp3     = (const float*)d_in[8];
    const float* W_mlp4     = (const float*)d_in[9];
    const float* W_down_s   = (const float*)d_in[10];
    const float* W_down_v   = (const float*)d_in[11];
    const int*   node_specie= (const int*)d_in[12];
    const int*   senders    = (const int*)d_in[13];
    const int*   receivers  = (const int*)d_in[14];
    float* out = (float*)d_out;

    // workspace layout
    float*  s1v1     = (float*)d_ws;                                  // N*128
    float*  agg      = s1v1 + (size_t)N_NODES * 128;                  // N*256
    float4* sortedVS = (float4*)(agg + (size_t)N_NODES * 256);        // E
    int*    cnt      = (int*)(sortedVS + N_EDGES);                    // N
    int*    cursor   = cnt + N_NODES;                                 // N
    int*    off      = cursor + N_NODES;                              // N+1
    float*  msgs     = (float*)(off + N_NODES + 2);                   // chunked

    size_t base_bytes = (size_t)((char*)msgs - (char*)d_ws);
    size_t margin = 1 << 20;
    size_t avail = (ws_size > base_bytes + margin) ? (ws_size - base_bytes - margin) : 0;
    long cap = (long)(avail / 1024);            // 256 floats per row
    if (cap > N_EDGES) cap = N_EDGES;
    if (cap < 4096)    cap = 4096;              // assume ws >= ~100 MB
    int  chunks = (int)((N_EDGES + cap - 1) / cap);
    long rows   = (((N_EDGES + chunks - 1) / chunks) + 255) & ~255L;  // mult of 256
    chunks = (int)((N_EDGES + rows - 1) / rows);

    hipFuncSetAttribute((const void*)k_edge,
                        hipFuncAttributeMaxDynamicSharedMemorySize, W_LDS_BYTES);

    hipMemsetAsync(cnt, 0, (size_t)N_NODES * sizeof(int), stream);

    dim3 gn((N_NODES + 255) / 256, 4);
    k_node_pre<<<gn, 256, 0, stream>>>(node_feats, node_specie, W_up_s, W_up_v,
                                       W_skip_s, W_skip_v, s1v1, out);
    k_hist<<<N_EDGES / 256, 256, 0, stream>>>(receivers, cnt);
    k_scan<<<1, 1024, 0, stream>>>(cnt, off, cursor);
    k_scatter<<<N_EDGES / 256, 256, 0, stream>>>(vectors, senders, receivers,
                                                 off, cursor, sortedVS);
    dim3 ga((N_NODES + 63) / 64, 4);
    for (int c = 0; c < chunks; ++c) {
        int r0 = (int)(c * rows);
        int r1 = (int)(r0 + rows); if (r1 > N_EDGES) r1 = N_EDGES;
        int nb = (int)((r1 - r0 + 255) / 256);
        k_edge<<<nb, 256, W_LDS_BYTES, stream>>>(sortedVS, W_mlp1, W_mlp2, W_mlp3,
                                                 W_mlp4, s1v1, msgs, r0, r1);
        k_agg<<<ga, 256, 0, stream>>>(msgs, off, agg, r0, r1, (c == 0) ? 1 : 0);
    }
    k_node_post<<<N_NODES, 256, 0, stream>>>(agg, W_down_s, W_down_v, out);
}